// Round 1
// baseline (1030.978 us; speedup 1.0000x reference)
//
#include <hip/hip_runtime.h>
#include <hip/hip_fp16.h>

#define EMB 2048
#define NH 16
#define HD 128
#define BATCH 4
#define SEQ 2048
#define MROWS (BATCH * SEQ)   // 8192

typedef __attribute__((ext_vector_type(8))) _Float16 f16x8;
typedef __attribute__((ext_vector_type(4))) float f32x4;

typedef __attribute__((address_space(3))) unsigned int lds_u32_t;
typedef const __attribute__((address_space(1))) unsigned int glb_u32_t;

__device__ __forceinline__ void async_copy16(void* lds, const void* g) {
    __builtin_amdgcn_global_load_lds((glb_u32_t*)g, (lds_u32_t*)lds, 16, 0, 0);
}

// ---------------- fp32 -> fp16 convert ----------------
__global__ void cvt_f32_f16(const float* __restrict__ in, __half* __restrict__ out, int n4) {
    int i = blockIdx.x * 256 + threadIdx.x;
    if (i < n4) {
        float4 v = ((const float4*)in)[i];
        __half2 a, b;
        a.x = __float2half(v.x); a.y = __float2half(v.y);
        b.x = __float2half(v.z); b.y = __float2half(v.w);
        ((__half2*)out)[2 * i]     = a;
        ((__half2*)out)[2 * i + 1] = b;
    }
}

// ---------------- shared GEMM mainloop: C(128x128) = A * B^T, K = 2048 ----------------
// A: row-major [*, 2048], B: row-major [*, 2048] (output col n = row n of B)
__device__ __forceinline__ void gemm_mainloop(const __half* __restrict__ A,
                                              const __half* __restrict__ B,
                                              int m0, int n0,
                                              short* sA, short* sB,
                                              f32x4 acc[4][4]) {
    const int tid  = threadIdx.x;
    const int wave = tid >> 6;
    const int lane = tid & 63;
    const int wr = wave >> 1, wc = wave & 1;
    const int frow = lane & 15;
    const int fk   = (lane >> 4) * 8;
    const int r0 = tid >> 2;            // staging row within 64-row half
    const int cb = (tid & 3) * 16;      // staging byte col within 64B row
    const char* gA = (const char*)A;
    const char* gB = (const char*)B;
    char* lA = (char*)sA;
    char* lB = (char*)sB;
    const int off0 = wave * 1024;         // c = 0 wave-uniform LDS base
    const int off1 = 4096 + wave * 1024;  // c = 1

    for (int kt = 0; kt < EMB; kt += 32) {
        size_t kb = (size_t)kt * 2;
        async_copy16(lA + off0, gA + ((size_t)(m0 + r0) * EMB) * 2 + kb + cb);
        async_copy16(lA + off1, gA + ((size_t)(m0 + 64 + r0) * EMB) * 2 + kb + cb);
        async_copy16(lB + off0, gB + ((size_t)(n0 + r0) * EMB) * 2 + kb + cb);
        async_copy16(lB + off1, gB + ((size_t)(n0 + 64 + r0) * EMB) * 2 + kb + cb);
        __syncthreads();   // drains global_load_lds (vmcnt0 before barrier)

        f16x8 af[4], bf[4];
#pragma unroll
        for (int i = 0; i < 4; i++)
            af[i] = *(const f16x8*)&sA[(wr * 64 + i * 16 + frow) * 32 + fk];
#pragma unroll
        for (int i = 0; i < 4; i++)
            bf[i] = *(const f16x8*)&sB[(wc * 64 + i * 16 + frow) * 32 + fk];
#pragma unroll
        for (int mi = 0; mi < 4; mi++)
#pragma unroll
            for (int ni = 0; ni < 4; ni++)
                acc[mi][ni] = __builtin_amdgcn_mfma_f32_16x16x32_f16(af[mi], bf[ni], acc[mi][ni], 0, 0, 0);
        __syncthreads();
    }
}

// ---------------- QKV projection + RoPE, writes (B,H,S,D) fp16 ----------------
__global__ __launch_bounds__(256) void gemm_qkv(const __half* __restrict__ X,
                                                const __half* __restrict__ Wq,
                                                const __half* __restrict__ Wk,
                                                const __half* __restrict__ Wv,
                                                __half* __restrict__ Q,
                                                __half* __restrict__ K,
                                                __half* __restrict__ V) {
    __shared__ short sA[128 * 32];
    __shared__ short sB[128 * 32];
    const int mblk = blockIdx.x;          // 0..63
    const int nb   = blockIdx.y;          // 0..47
    const int wsel = nb >> 4;             // 0=Q 1=K 2=V
    const int nloc = (nb & 15) * 128;
    const __half* W = (wsel == 0) ? Wq : ((wsel == 1) ? Wk : Wv);

    f32x4 z = {0.f, 0.f, 0.f, 0.f};
    f32x4 acc[4][4];
#pragma unroll
    for (int i = 0; i < 4; i++)
#pragma unroll
        for (int j = 0; j < 4; j++) acc[i][j] = z;

    gemm_mainloop(X, W, mblk * 128, nloc, sA, sB, acc);

    const int lane = threadIdx.x & 63;
    const int wave = threadIdx.x >> 6;
    const int wr = wave >> 1, wc = wave & 1;
    const int q4 = lane >> 4;
    __half* Obuf = (wsel == 0) ? Q : ((wsel == 1) ? K : V);
    const bool rope = (wsel < 2);

#pragma unroll
    for (int ni = 0; ni < 4; ni++) {
        int n = nloc + wc * 64 + ni * 16 + (lane & 15);
        int h = n >> 7, d = n & 127;
        float invf = rope ? __expf(-((float)(d & ~1)) * (9.210340371976184f / 128.0f)) : 0.f;
#pragma unroll
        for (int mi = 0; mi < 4; mi++) {
#pragma unroll
            for (int r = 0; r < 4; r++) {
                int m = mblk * 128 + wr * 64 + mi * 16 + q4 * 4 + r;
                int b = m >> 11, s = m & 2047;
                float v = acc[mi][ni][r];
                float res;
                if (rope) {
                    float p = __shfl_xor(v, 1);
                    float ang = (float)s * invf;
                    float sn, cs;
                    __sincosf(ang, &sn, &cs);
                    if ((lane & 1) == 0) res = v * cs - p * sn;  // even d: x1'
                    else                 res = v * cs + p * sn;  // odd d:  x2'
                } else {
                    res = v;
                }
                float pr = __shfl_xor(res, 1);
                if ((lane & 1) == 0) {
                    __half2 hv;
                    hv.x = __float2half(res);
                    hv.y = __float2half(pr);
                    size_t off = ((size_t)(b * NH + h) * SEQ + s) * HD + d;  // d even
                    *(__half2*)(Obuf + off) = hv;
                }
            }
        }
    }
}

// ---------------- causal flash attention ----------------
#define LDK 136   // K/P tile pitch (shorts)
#define LDV 136   // V^T tile pitch (shorts)

__global__ __launch_bounds__(256, 2) void attn_kernel(const __half* __restrict__ Q,
                                                      const __half* __restrict__ K,
                                                      const __half* __restrict__ V,
                                                      __half* __restrict__ CTX) {
    __shared__ short sKP[128 * LDK];   // K tile (n,d); reused as P tile (m,n)
    __shared__ short sVT[128 * LDV];   // V^T tile (d,n)
    const int qt = blockIdx.x;         // 0..15
    const int bh = blockIdx.y;         // 0..63
    const int b = bh >> 4, h = bh & 15;
    const int tid = threadIdx.x;
    const int wave = tid >> 6, lane = tid & 63;
    const int fr = lane & 15, q4 = lane >> 4;
    const size_t headoff = (size_t)bh * SEQ * HD;
    const __half* Qh = Q + headoff;
    const __half* Kh = K + headoff;
    const __half* Vh = V + headoff;

    // Q fragments in registers: rows qt*128 + wave*32 + mi*16 + fr, k = ds*32 + q4*8
    f16x8 qf[2][4];
#pragma unroll
    for (int mi = 0; mi < 2; mi++)
#pragma unroll
        for (int ds = 0; ds < 4; ds++)
            qf[mi][ds] = *(const f16x8*)(Qh + (size_t)(qt * 128 + wave * 32 + mi * 16 + fr) * HD + ds * 32 + q4 * 8);

    f32x4 z = {0.f, 0.f, 0.f, 0.f};
    f32x4 accO[2][8];
#pragma unroll
    for (int i = 0; i < 2; i++)
#pragma unroll
        for (int j = 0; j < 8; j++) accO[i][j] = z;
    float mrow[2][4], lrow[2][4];
#pragma unroll
    for (int i = 0; i < 2; i++)
#pragma unroll
        for (int r = 0; r < 4; r++) { mrow[i][r] = -INFINITY; lrow[i][r] = 0.f; }

    const float scale = 0.08838834764831845f;  // 1/sqrt(128)

    for (int kt = 0; kt <= qt; kt++) {
        // ---- stage K tile (row-major n,d with pitch LDK) ----
#pragma unroll
        for (int j = 0; j < 8; j++) {
            int cid = j * 256 + tid;
            int n = cid >> 4, c = cid & 15;
            f16x8 kv = *(const f16x8*)(Kh + (size_t)(kt * 128 + n) * HD + c * 8);
            *(f16x8*)&sKP[n * LDK + c * 8] = kv;
        }
        // ---- stage V^T tile: thread owns column n, walks d ----
        {
            int nn = tid & 127;
            int dh = (tid >> 7) * 64;
#pragma unroll
            for (int j = 0; j < 8; j++) {
                int d0 = dh + j * 8;
                f16x8 vv = *(const f16x8*)(Vh + (size_t)(kt * 128 + nn) * HD + d0);
#pragma unroll
                for (int e = 0; e < 8; e++)
                    sVT[(d0 + e) * LDV + nn] = ((short*)&vv)[e];
            }
        }
        __syncthreads();

        // ---- S = Q K^T (wave rows x 128 cols) ----
        f32x4 accS[2][8];
#pragma unroll
        for (int i = 0; i < 2; i++)
#pragma unroll
            for (int j = 0; j < 8; j++) accS[i][j] = z;
#pragma unroll
        for (int ds = 0; ds < 4; ds++) {
            f16x8 kf[8];
#pragma unroll
            for (int ni = 0; ni < 8; ni++)
                kf[ni] = *(const f16x8*)&sKP[(ni * 16 + fr) * LDK + ds * 32 + q4 * 8];
#pragma unroll
            for (int mi = 0; mi < 2; mi++)
#pragma unroll
                for (int ni = 0; ni < 8; ni++)
                    accS[mi][ni] = __builtin_amdgcn_mfma_f32_16x16x32_f16(qf[mi][ds], kf[ni], accS[mi][ni], 0, 0, 0);
        }

        // ---- online softmax (fp32, wave-local) ----
#pragma unroll
        for (int mi = 0; mi < 2; mi++) {
#pragma unroll
            for (int r = 0; r < 4; r++) {
                int qrow = qt * 128 + wave * 32 + mi * 16 + q4 * 4 + r;
                float vals[8];
                float mx = -INFINITY;
#pragma unroll
                for (int ni = 0; ni < 8; ni++) {
                    int kcol = kt * 128 + ni * 16 + fr;
                    float x = accS[mi][ni][r] * scale;
                    if (kcol > qrow) x = -INFINITY;
                    vals[ni] = x;
                    mx = fmaxf(mx, x);
                }
#pragma unroll
                for (int off = 1; off < 16; off <<= 1)
                    mx = fmaxf(mx, __shfl_xor(mx, off));
                float mnew = fmaxf(mrow[mi][r], mx);
                float alpha = __expf(mrow[mi][r] - mnew);
                mrow[mi][r] = mnew;
                float rs = 0.f;
#pragma unroll
                for (int ni = 0; ni < 8; ni++) {
                    float p = __expf(vals[ni] - mnew);
                    rs += p;
                    accS[mi][ni][r] = p;   // stash P for LDS write
                }
#pragma unroll
                for (int off = 1; off < 16; off <<= 1)
                    rs += __shfl_xor(rs, off);
                lrow[mi][r] = lrow[mi][r] * alpha + rs;
#pragma unroll
                for (int di = 0; di < 8; di++)
                    accO[mi][di][r] *= alpha;
            }
        }

        __syncthreads();   // all waves done reading K before P overwrites sKP

        // ---- write P (pair-packed __half2, even lanes) ----
#pragma unroll
        for (int mi = 0; mi < 2; mi++)
#pragma unroll
            for (int ni = 0; ni < 8; ni++)
#pragma unroll
                for (int r = 0; r < 4; r++) {
                    float p = accS[mi][ni][r];
                    float pp = __shfl_xor(p, 1);
                    if ((lane & 1) == 0) {
                        int row = wave * 32 + mi * 16 + q4 * 4 + r;
                        int col = ni * 16 + fr;   // even
                        __half2 h2;
                        h2.x = __float2half(p);
                        h2.y = __float2half(pp);
                        *(__half2*)&sKP[row * LDK + col] = h2;
                    }
                }
        __syncthreads();

        // ---- O += P V ----
#pragma unroll
        for (int ns = 0; ns < 4; ns++) {
            f16x8 pf[2], vf[8];
#pragma unroll
            for (int mi = 0; mi < 2; mi++)
                pf[mi] = *(const f16x8*)&sKP[(wave * 32 + mi * 16 + fr) * LDK + ns * 32 + q4 * 8];
#pragma unroll
            for (int di = 0; di < 8; di++)
                vf[di] = *(const f16x8*)&sVT[(di * 16 + fr) * LDV + ns * 32 + q4 * 8];
#pragma unroll
            for (int mi = 0; mi < 2; mi++)
#pragma unroll
                for (int di = 0; di < 8; di++)
                    accO[mi][di] = __builtin_amdgcn_mfma_f32_16x16x32_f16(pf[mi], vf[di], accO[mi][di], 0, 0, 0);
        }
        __syncthreads();   // PV reads done before next tile's staging
    }

    // ---- epilogue: O / l, write ctx (B,S,H*D) fp16 ----
    float linv[2][4];
#pragma unroll
    for (int mi = 0; mi < 2; mi++)
#pragma unroll
        for (int r = 0; r < 4; r++) linv[mi][r] = 1.f / lrow[mi][r];

#pragma unroll
    for (int mi = 0; mi < 2; mi++)
#pragma unroll
        for (int di = 0; di < 8; di++)
#pragma unroll
            for (int r = 0; r < 4; r++) {
                float o = accO[mi][di][r] * linv[mi][r];
                float po = __shfl_xor(o, 1);
                if ((lane & 1) == 0) {
                    int srow = qt * 128 + wave * 32 + mi * 16 + q4 * 4 + r;
                    int d = di * 16 + fr;  // even
                    size_t off = ((size_t)(b * SEQ + srow)) * EMB + h * HD + d;
                    __half2 h2;
                    h2.x = __float2half(o);
                    h2.y = __float2half(po);
                    *(__half2*)&CTX[off] = h2;
                }
            }
}

// ---------------- output projection: out(fp32) = CTX * Wo^T ----------------
__global__ __launch_bounds__(256) void gemm_out(const __half* __restrict__ CTX,
                                                const __half* __restrict__ Wo,
                                                float* __restrict__ out) {
    __shared__ short sA[128 * 32];
    __shared__ short sB[128 * 32];
    f32x4 z = {0.f, 0.f, 0.f, 0.f};
    f32x4 acc[4][4];
#pragma unroll
    for (int i = 0; i < 4; i++)
#pragma unroll
        for (int j = 0; j < 4; j++) acc[i][j] = z;

    gemm_mainloop(CTX, Wo, blockIdx.x * 128, blockIdx.y * 128, sA, sB, acc);

    const int lane = threadIdx.x & 63;
    const int wave = threadIdx.x >> 6;
    const int wr = wave >> 1, wc = wave & 1;
    const int q4 = lane >> 4;
#pragma unroll
    for (int mi = 0; mi < 4; mi++)
#pragma unroll
        for (int ni = 0; ni < 4; ni++)
#pragma unroll
            for (int r = 0; r < 4; r++) {
                int m = blockIdx.x * 128 + wr * 64 + mi * 16 + q4 * 4 + r;
                int n = blockIdx.y * 128 + wc * 64 + ni * 16 + (lane & 15);
                out[(size_t)m * EMB + n] = acc[mi][ni][r];
            }
}

extern "C" void kernel_launch(void* const* d_in, const int* in_sizes, int n_in,
                              void* d_out, int out_size, void* d_ws, size_t ws_size,
                              hipStream_t stream) {
    const float* x  = (const float*)d_in[0];
    const float* Wq = (const float*)d_in[1];
    const float* Wk = (const float*)d_in[2];
    const float* Wv = (const float*)d_in[3];
    const float* Wo = (const float*)d_in[4];
    float* out = (float*)d_out;

    char* ws = (char*)d_ws;
    size_t off = 0;
    __half* Xh  = (__half*)(ws + off); off += (size_t)MROWS * EMB * 2;   // 33.5 MB (reused as CTX)
    __half* Wqh = (__half*)(ws + off); off += (size_t)EMB * EMB * 2;
    __half* Wkh = (__half*)(ws + off); off += (size_t)EMB * EMB * 2;
    __half* Wvh = (__half*)(ws + off); off += (size_t)EMB * EMB * 2;
    __half* Woh = (__half*)(ws + off); off += (size_t)EMB * EMB * 2;
    __half* Qb  = (__half*)(ws + off); off += (size_t)MROWS * HD * NH * 2 / NH; // = MROWS*EMB? no: B*H*S*D = MROWS*HD*NH/NH
    // B*H*S*D = 4*16*2048*128 = 16777216 halves
    off = (size_t)(Qb - (__half*)ws) * 2 + (size_t)16777216 * 2;
    __half* Kb  = (__half*)(ws + off); off += (size_t)16777216 * 2;
    __half* Vb  = (__half*)(ws + off); off += (size_t)16777216 * 2;
    __half* Cb  = Xh;   // X is dead after gemm_qkv

    // converts
    cvt_f32_f16<<<16384, 256, 0, stream>>>(x,  Xh,  4194304);
    cvt_f32_f16<<<4096,  256, 0, stream>>>(Wq, Wqh, 1048576);
    cvt_f32_f16<<<4096,  256, 0, stream>>>(Wk, Wkh, 1048576);
    cvt_f32_f16<<<4096,  256, 0, stream>>>(Wv, Wvh, 1048576);
    cvt_f32_f16<<<4096,  256, 0, stream>>>(Wo, Woh, 1048576);

    // QKV projection + RoPE
    gemm_qkv<<<dim3(64, 48), 256, 0, stream>>>(Xh, Wqh, Wkh, Wvh, Qb, Kb, Vb);

    // causal flash attention
    attn_kernel<<<dim3(16, 64), 256, 0, stream>>>(Qb, Kb, Vb, Cb);

    // output projection
    gemm_out<<<dim3(64, 16), 256, 0, stream>>>(Cb, Woh, out);
}